// Round 12
// baseline (249.639 us; speedup 1.0000x reference)
//
#include <hip/hip_runtime.h>
#include <hip/hip_bf16.h>

typedef __attribute__((ext_vector_type(8))) short short8;
typedef __attribute__((ext_vector_type(4))) float f32x4;
typedef unsigned int u32;

constexpr int N = 1024, M = 1024, D = 64, BH = 128;
constexpr size_t ATTN_ELEMS = (size_t)BH * N * M;     // 134217728
constexpr size_t QKV_ELEMS  = (size_t)BH * N * D;     // 8388608
constexpr int PB_BLOCKS = 2048;
constexpr int KCONV_BLOCKS = 512;
constexpr int COPY_BLOCKS_PER = 256;                   // per q/k/v tensor
constexpr int BGROUP = 8;                              // batches per attn block
constexpr int BR = 32, BC = 256;                       // attn tile: 32 rows x 256 cols

__device__ __forceinline__ short f2b(float x) {
    __hip_bfloat16 h = __float2bfloat16(x);
    return *reinterpret_cast<short*>(&h);
}

__device__ __forceinline__ void gl_lds16(const void* g, void* l) {
    __builtin_amdgcn_global_load_lds(
        (const __attribute__((address_space(1))) u32*)g,
        (__attribute__((address_space(3))) u32*)l, 16, 0, 0);
}

// Fused prep (r6 version, proven):
//   [0, PB_BLOCKS)            : pb[n,m] = pos_enc[n,m,:].w + b
//   [.., +KCONV_BLOCKS)       : keys fp32 -> bf16, PRE-SWIZZLED slot order
//   [.., +ncopy)              : q/k/v pass-through copies
//   last                      : scale = sum(w)/sqrt(16)
__global__ void prep_kernel(const float* __restrict__ q, const float* __restrict__ k,
                            const float* __restrict__ v, const float* __restrict__ pos,
                            const float* __restrict__ w, const float* __restrict__ b,
                            float* __restrict__ pb, short* __restrict__ kbf,
                            float* __restrict__ scale_p,
                            float* __restrict__ qout, float* __restrict__ kout,
                            float* __restrict__ vout, int ncopy) {
    const int bid = blockIdx.x, tid = threadIdx.x;
    if (bid < PB_BLOCKS) {
        const int lane16 = tid & 15;
        const f32x4 w4 = ((const f32x4*)w)[lane16];
        const float bias = b[0];
        const int group = (bid * 256 + tid) >> 4;
        const int ngroups = (PB_BLOCKS * 256) >> 4;
        for (int pair = group; pair < N * M; pair += ngroups) {
            f32x4 p = __builtin_nontemporal_load((const f32x4*)pos + (size_t)pair * 16 + lane16);
            float s = p[0]*w4[0] + p[1]*w4[1] + p[2]*w4[2] + p[3]*w4[3];
            s += __shfl_xor(s, 1);
            s += __shfl_xor(s, 2);
            s += __shfl_xor(s, 4);
            s += __shfl_xor(s, 8);
            if (lane16 == 0) pb[pair] = s + bias;
        }
    } else if (bid < PB_BLOCKS + KCONV_BLOCKS) {
        const int cid = bid - PB_BLOCKS;
        const int total_slots = BH * N * 8;        // 16B slots, 1048576
        for (int gs = cid * 256 + tid; gs < total_slots; gs += KCONV_BLOCKS * 256) {
            const int qs = gs & 7, gr = (gs >> 3) & (N - 1), bb = gs >> 13;
            const float* src = k + ((size_t)bb * N + gr) * D + (qs ^ (gr & 7)) * 8;
            f32x4 x0 = ((const f32x4*)src)[0], x1 = ((const f32x4*)src)[1];
            short8 pk;
#pragma unroll
            for (int e = 0; e < 4; e++) { pk[e] = f2b(x0[e]); pk[4 + e] = f2b(x1[e]); }
            *(short8*)&kbf[(size_t)gs * 8] = pk;
        }
    } else if (bid < PB_BLOCKS + KCONV_BLOCKS + ncopy) {
        const int cid = bid - PB_BLOCKS - KCONV_BLOCKS;
        const int which = cid >> 8, lid = cid & 255;
        const f32x4* __restrict__ src = (which == 0) ? (const f32x4*)q
                                      : (which == 1) ? (const f32x4*)k : (const f32x4*)v;
        f32x4* __restrict__ dst = (which == 0) ? (f32x4*)qout
                                : (which == 1) ? (f32x4*)kout : (f32x4*)vout;
        const int nel4 = (int)(QKV_ELEMS / 4);
        for (int i = lid * 256 + tid; i < nel4; i += COPY_BLOCKS_PER * 256) {
            f32x4 x = __builtin_nontemporal_load(src + i);
            __builtin_nontemporal_store(x, dst + i);
        }
    } else {
        if (tid < 64) {
            float val = w[tid];
#pragma unroll
            for (int o = 32; o > 0; o >>= 1) val += __shfl_down(val, o);
            if (tid == 0) scale_p[0] = val * 0.25f;
        }
    }
}

// attn = (K K^T)*scale + pb.  r6 structure EXACTLY (32x256 tile, single 36KB
// buffer, plain __syncthreads, pf in registers, gl_lds staging from
// pre-swizzled bf16 keys) + ONE change: NON-TEMPORAL epilogue stores so the
// 512MB streaming write doesn't evict kbf/pb from L2 (staging re-reads them
// 36x; r3->r4 A/B showed removing NT attn stores cost ~6us).
__launch_bounds__(256)
__global__ void attn_kernel(const short* __restrict__ kbf, const float* __restrict__ pb,
                            const float* __restrict__ scale_p, float* __restrict__ out) {
    __shared__ short lK[(BR + BC) * 64];          // 36KB
    const int pos = blockIdx.x;                   // 0..127
    const int tr = pos >> 2, tc = pos & 3;        // 32 row-tiles x 4 col-tiles
    const int batch0 = blockIdx.y * BGROUP;
    const int tid = threadIdx.x;
    const float scale = scale_p[0];

    const int lane = tid & 63, wv = tid >> 6;     // 4 waves
    const int wr = wv >> 1, wc = wv & 1;          // 2x2: 16 rows x 128 cols each
    const int frow = lane & 15;
    const int kslot = lane >> 4;

    const int orow = tr * BR + wr * 16 + (lane >> 4) * 4;   // + r
    const int ocol = tc * BC + wc * 128 + (lane & 15);      // + j*16

    // pb fragments in accumulator layout — reused for all BGROUP batches.
    f32x4 pf[8];
#pragma unroll
    for (int j = 0; j < 8; j++)
#pragma unroll
        for (int r = 0; r < 4; r++)
            pf[j][r] = pb[(size_t)(orow + r) * M + (ocol + j * 16)];

    for (int t = 0; t < BGROUP; ++t) {
        const short* __restrict__ Kb = kbf + (size_t)(batch0 + t) * N * 64;

        // Stage A rows [tr*32,+32) and B rows [tc*256,+256): 2304 16B slots,
        // direct global->LDS (source pre-swizzled, LDS linear).
#pragma unroll
        for (int it = 0; it < 9; ++it) {
            const int slot = it * 256 + tid;
            const int row = slot >> 3, qs = slot & 7;
            const int gr = (row < BR) ? (tr * BR + row) : (tc * BC + (row - BR));
            gl_lds16(Kb + (size_t)gr * 64 + qs * 8, &lK[slot * 8]);
        }
        __syncthreads();

        f32x4 acc[8] = {};
#pragma unroll
        for (int h = 0; h < 2; ++h) {             // k halves (k=0..31, 32..63)
            const int ra = wr * 16 + frow;
            short8 a = *(const short8*)&lK[ra * 64 + ((h * 4 + kslot) ^ (ra & 7)) * 8];
#pragma unroll
            for (int j = 0; j < 8; ++j) {
                const int rb = BR + wc * 128 + j * 16 + frow;
                short8 bf = *(const short8*)&lK[rb * 64 + ((h * 4 + kslot) ^ (rb & 7)) * 8];
                acc[j] = __builtin_amdgcn_mfma_f32_16x16x32_bf16(a, bf, acc[j], 0, 0, 0);
            }
        }

        const size_t obase = (size_t)(batch0 + t) * N * M;
#pragma unroll
        for (int j = 0; j < 8; ++j)
#pragma unroll
            for (int r = 0; r < 4; ++r) {
                float val = acc[j][r] * scale + pf[j][r];
                __builtin_nontemporal_store(val,
                    &out[obase + (size_t)(orow + r) * M + (ocol + j * 16)]);
            }
        __syncthreads();                          // LDS safe to overwrite next t
    }
}

extern "C" void kernel_launch(void* const* d_in, const int* in_sizes, int n_in,
                              void* d_out, int out_size, void* d_ws, size_t ws_size,
                              hipStream_t stream) {
    const float* queries = (const float*)d_in[0];
    const float* keys    = (const float*)d_in[1];
    const float* values  = (const float*)d_in[2];
    const float* pos_enc = (const float*)d_in[3];
    const float* w_pos   = (const float*)d_in[4];
    const float* b_pos   = (const float*)d_in[5];

    float* out  = (float*)d_out;
    float* qout = out + ATTN_ELEMS;
    float* kout = qout + QKV_ELEMS;
    float* vout = kout + QKV_ELEMS;

    // ws layout: pb (N*M floats) | scale (16 floats) | kbf (BH*N*64 shorts)
    const size_t need_ws = ((size_t)N * M + 16) * sizeof(float)
                         + (size_t)BH * N * 64 * sizeof(short);
    const int npos = (N / BR) * (M / BC);         // 128 tile positions

    if (ws_size >= need_ws) {
        float* pb      = (float*)d_ws;
        float* scale_p = pb + (size_t)N * M;
        short* kbf     = (short*)(scale_p + 16);
        const int ncopy = 3 * COPY_BLOCKS_PER;
        prep_kernel<<<dim3(PB_BLOCKS + KCONV_BLOCKS + ncopy + 1), dim3(256), 0, stream>>>(
            queries, keys, values, pos_enc, w_pos, b_pos, pb, kbf, scale_p,
            qout, kout, vout, ncopy);
        attn_kernel<<<dim3(npos, BH / BGROUP), dim3(256), 0, stream>>>(kbf, pb, scale_p, out);
    } else {
        // Fallback: stash pb + scale + kbf in the q/k region of d_out (20MB),
        // run prep without copies, attn, then copy q/k/v after.
        float* pb      = qout;
        float* scale_p = pb + (size_t)N * M;
        short* kbf     = (short*)(scale_p + 16);
        prep_kernel<<<dim3(PB_BLOCKS + KCONV_BLOCKS + 1), dim3(256), 0, stream>>>(
            queries, keys, values, pos_enc, w_pos, b_pos, pb, kbf, scale_p,
            qout, kout, vout, /*ncopy=*/0);
        attn_kernel<<<dim3(npos, BH / BGROUP), dim3(256), 0, stream>>>(kbf, pb, scale_p, out);
        hipMemcpyAsync(qout, queries, QKV_ELEMS * sizeof(float), hipMemcpyDeviceToDevice, stream);
        hipMemcpyAsync(kout, keys,    QKV_ELEMS * sizeof(float), hipMemcpyDeviceToDevice, stream);
        hipMemcpyAsync(vout, values,  QKV_ELEMS * sizeof(float), hipMemcpyDeviceToDevice, stream);
    }
}

// Round 13
// 214.912 us; speedup vs baseline: 1.1616x; 1.1616x over previous
//
#include <hip/hip_runtime.h>
#include <hip/hip_bf16.h>

typedef __attribute__((ext_vector_type(8))) short short8;
typedef __attribute__((ext_vector_type(4))) float f32x4;
typedef unsigned int u32;

constexpr int N = 1024, M = 1024, D = 64, BH = 128;
constexpr size_t ATTN_ELEMS = (size_t)BH * N * M;     // 134217728
constexpr size_t QKV_ELEMS  = (size_t)BH * N * D;     // 8388608
constexpr int PB_BLOCKS = 2048;
constexpr int KCONV_BLOCKS = 512;
constexpr int COPY_BLOCKS_PER = 256;                   // per q/k/v tensor
constexpr int BGROUP = 8;                              // batches per attn block
constexpr int BR = 64, BC = 128;                       // attn tile: 64 rows x 128 cols
constexpr int STAGE_SLOTS = (BR + BC) * 8;             // 1536 16B slots
constexpr int SPT = STAGE_SLOTS / 256;                 // 6 per thread

__device__ __forceinline__ short f2b(float x) {
    __hip_bfloat16 h = __float2bfloat16(x);
    return *reinterpret_cast<short*>(&h);
}

__device__ __forceinline__ void gl_lds16(const void* g, void* l) {
    __builtin_amdgcn_global_load_lds(
        (const __attribute__((address_space(1))) u32*)g,
        (__attribute__((address_space(3))) u32*)l, 16, 0, 0);
}

// Fused prep (r6 version, proven):
//   [0, PB_BLOCKS)            : pb[n,m] = pos_enc[n,m,:].w + b
//   [.., +KCONV_BLOCKS)       : keys fp32 -> bf16, PRE-SWIZZLED slot order
//   [.., +ncopy)              : q/k/v pass-through copies
//   last                      : scale = sum(w)/sqrt(16)
__global__ void prep_kernel(const float* __restrict__ q, const float* __restrict__ k,
                            const float* __restrict__ v, const float* __restrict__ pos,
                            const float* __restrict__ w, const float* __restrict__ b,
                            float* __restrict__ pb, short* __restrict__ kbf,
                            float* __restrict__ scale_p,
                            float* __restrict__ qout, float* __restrict__ kout,
                            float* __restrict__ vout, int ncopy) {
    const int bid = blockIdx.x, tid = threadIdx.x;
    if (bid < PB_BLOCKS) {
        const int lane16 = tid & 15;
        const f32x4 w4 = ((const f32x4*)w)[lane16];
        const float bias = b[0];
        const int group = (bid * 256 + tid) >> 4;
        const int ngroups = (PB_BLOCKS * 256) >> 4;
        for (int pair = group; pair < N * M; pair += ngroups) {
            f32x4 p = __builtin_nontemporal_load((const f32x4*)pos + (size_t)pair * 16 + lane16);
            float s = p[0]*w4[0] + p[1]*w4[1] + p[2]*w4[2] + p[3]*w4[3];
            s += __shfl_xor(s, 1);
            s += __shfl_xor(s, 2);
            s += __shfl_xor(s, 4);
            s += __shfl_xor(s, 8);
            if (lane16 == 0) pb[pair] = s + bias;
        }
    } else if (bid < PB_BLOCKS + KCONV_BLOCKS) {
        const int cid = bid - PB_BLOCKS;
        const int total_slots = BH * N * 8;        // 16B slots, 1048576
        for (int gs = cid * 256 + tid; gs < total_slots; gs += KCONV_BLOCKS * 256) {
            const int qs = gs & 7, gr = (gs >> 3) & (N - 1), bb = gs >> 13;
            const float* src = k + ((size_t)bb * N + gr) * D + (qs ^ (gr & 7)) * 8;
            f32x4 x0 = ((const f32x4*)src)[0], x1 = ((const f32x4*)src)[1];
            short8 pk;
#pragma unroll
            for (int e = 0; e < 4; e++) { pk[e] = f2b(x0[e]); pk[4 + e] = f2b(x1[e]); }
            *(short8*)&kbf[(size_t)gs * 8] = pk;
        }
    } else if (bid < PB_BLOCKS + KCONV_BLOCKS + ncopy) {
        const int cid = bid - PB_BLOCKS - KCONV_BLOCKS;
        const int which = cid >> 8, lid = cid & 255;
        const f32x4* __restrict__ src = (which == 0) ? (const f32x4*)q
                                      : (which == 1) ? (const f32x4*)k : (const f32x4*)v;
        f32x4* __restrict__ dst = (which == 0) ? (f32x4*)qout
                                : (which == 1) ? (f32x4*)kout : (f32x4*)vout;
        const int nel4 = (int)(QKV_ELEMS / 4);
        for (int i = lid * 256 + tid; i < nel4; i += COPY_BLOCKS_PER * 256) {
            f32x4 x = __builtin_nontemporal_load(src + i);
            __builtin_nontemporal_store(x, dst + i);
        }
    } else {
        if (tid < 64) {
            float val = w[tid];
#pragma unroll
            for (int o = 32; o > 0; o >>= 1) val += __shfl_down(val, o);
            if (tid == 0) scale_p[0] = val * 0.25f;
        }
    }
}

// attn = (K K^T)*scale + pb.  r6 loop structure (single LDS buffer, plain
// __syncthreads, pf in regs, gl_lds from pre-swizzled bf16 keys, plain
// stores) with a 64x128 tile: staged bytes per output byte drop 1.125->0.75
// (staging traffic 576->384MB) and gl_lds per barrier 9->6.  LDS 24KB.
// __launch_bounds__(256,4) pins VGPR<=128 for 16 waves/CU.
__launch_bounds__(256, 4)
__global__ void attn_kernel(const short* __restrict__ kbf, const float* __restrict__ pb,
                            const float* __restrict__ scale_p, float* __restrict__ out) {
    __shared__ short lK[(BR + BC) * 64];          // 24KB
    const int pos = blockIdx.x;                   // 0..127
    const int tr = pos >> 3, tc = pos & 7;        // 16 row-tiles x 8 col-tiles
    const int batch0 = blockIdx.y * BGROUP;
    const int tid = threadIdx.x;
    const float scale = scale_p[0];

    const int lane = tid & 63, wv = tid >> 6;     // 4 waves
    const int wr = wv >> 1, wc = wv & 1;          // 2x2: 32 rows x 64 cols each
    const int frow = lane & 15;
    const int kslot = lane >> 4;

    const int orow = tr * BR + wr * 32 + (lane >> 4) * 4;   // + i*16 + r
    const int ocol = tc * BC + wc * 64 + (lane & 15);       // + j*16

    // pb fragments in accumulator layout — reused for all BGROUP batches.
    f32x4 pf[2][4];
#pragma unroll
    for (int i = 0; i < 2; i++)
#pragma unroll
        for (int j = 0; j < 4; j++)
#pragma unroll
            for (int r = 0; r < 4; r++)
                pf[i][j][r] = pb[(size_t)(orow + i * 16 + r) * M + (ocol + j * 16)];

    for (int t = 0; t < BGROUP; ++t) {
        const short* __restrict__ Kb = kbf + (size_t)(batch0 + t) * N * 64;

        // Stage A rows [tr*64,+64) and B rows [tc*128,+128): 1536 16B slots.
#pragma unroll
        for (int it = 0; it < SPT; ++it) {
            const int slot = it * 256 + tid;
            const int row = slot >> 3, qs = slot & 7;
            const int gr = (row < BR) ? (tr * BR + row) : (tc * BC + (row - BR));
            gl_lds16(Kb + (size_t)gr * 64 + qs * 8, &lK[slot * 8]);
        }
        __syncthreads();

        f32x4 acc[2][4] = {};
#pragma unroll
        for (int h = 0; h < 2; ++h) {             // k halves (k=0..31, 32..63)
            short8 a[2];
#pragma unroll
            for (int i = 0; i < 2; ++i) {
                const int ra = wr * 32 + i * 16 + frow;
                a[i] = *(const short8*)&lK[ra * 64 + ((h * 4 + kslot) ^ (ra & 7)) * 8];
            }
#pragma unroll
            for (int j = 0; j < 4; ++j) {
                const int rb = BR + wc * 64 + j * 16 + frow;
                short8 bf = *(const short8*)&lK[rb * 64 + ((h * 4 + kslot) ^ (rb & 7)) * 8];
#pragma unroll
                for (int i = 0; i < 2; ++i)
                    acc[i][j] = __builtin_amdgcn_mfma_f32_16x16x32_bf16(a[i], bf, acc[i][j], 0, 0, 0);
            }
        }

        const size_t obase = (size_t)(batch0 + t) * N * M;
#pragma unroll
        for (int i = 0; i < 2; ++i)
#pragma unroll
            for (int j = 0; j < 4; ++j)
#pragma unroll
                for (int r = 0; r < 4; ++r) {
                    out[obase + (size_t)(orow + i * 16 + r) * M + (ocol + j * 16)]
                        = acc[i][j][r] * scale + pf[i][j][r];
                }
        __syncthreads();                          // LDS safe to overwrite next t
    }
}

extern "C" void kernel_launch(void* const* d_in, const int* in_sizes, int n_in,
                              void* d_out, int out_size, void* d_ws, size_t ws_size,
                              hipStream_t stream) {
    const float* queries = (const float*)d_in[0];
    const float* keys    = (const float*)d_in[1];
    const float* values  = (const float*)d_in[2];
    const float* pos_enc = (const float*)d_in[3];
    const float* w_pos   = (const float*)d_in[4];
    const float* b_pos   = (const float*)d_in[5];

    float* out  = (float*)d_out;
    float* qout = out + ATTN_ELEMS;
    float* kout = qout + QKV_ELEMS;
    float* vout = kout + QKV_ELEMS;

    // ws layout: pb (N*M floats) | scale (16 floats) | kbf (BH*N*64 shorts)
    const size_t need_ws = ((size_t)N * M + 16) * sizeof(float)
                         + (size_t)BH * N * 64 * sizeof(short);
    const int npos = (N / BR) * (M / BC);         // 128 tile positions

    if (ws_size >= need_ws) {
        float* pb      = (float*)d_ws;
        float* scale_p = pb + (size_t)N * M;
        short* kbf     = (short*)(scale_p + 16);
        const int ncopy = 3 * COPY_BLOCKS_PER;
        prep_kernel<<<dim3(PB_BLOCKS + KCONV_BLOCKS + ncopy + 1), dim3(256), 0, stream>>>(
            queries, keys, values, pos_enc, w_pos, b_pos, pb, kbf, scale_p,
            qout, kout, vout, ncopy);
        attn_kernel<<<dim3(npos, BH / BGROUP), dim3(256), 0, stream>>>(kbf, pb, scale_p, out);
    } else {
        // Fallback: stash pb + scale + kbf in the q/k region of d_out (20MB),
        // run prep without copies, attn, then copy q/k/v after.
        float* pb      = qout;
        float* scale_p = pb + (size_t)N * M;
        short* kbf     = (short*)(scale_p + 16);
        prep_kernel<<<dim3(PB_BLOCKS + KCONV_BLOCKS + 1), dim3(256), 0, stream>>>(
            queries, keys, values, pos_enc, w_pos, b_pos, pb, kbf, scale_p,
            qout, kout, vout, /*ncopy=*/0);
        attn_kernel<<<dim3(npos, BH / BGROUP), dim3(256), 0, stream>>>(kbf, pb, scale_p, out);
        hipMemcpyAsync(qout, queries, QKV_ELEMS * sizeof(float), hipMemcpyDeviceToDevice, stream);
        hipMemcpyAsync(kout, keys,    QKV_ELEMS * sizeof(float), hipMemcpyDeviceToDevice, stream);
        hipMemcpyAsync(vout, values,  QKV_ELEMS * sizeof(float), hipMemcpyDeviceToDevice, stream);
    }
}

// Round 14
// 212.981 us; speedup vs baseline: 1.1721x; 1.0091x over previous
//
#include <hip/hip_runtime.h>
#include <hip/hip_bf16.h>

typedef __attribute__((ext_vector_type(8))) short short8;
typedef __attribute__((ext_vector_type(4))) float f32x4;
typedef unsigned int u32;

constexpr int N = 1024, M = 1024, D = 64, BH = 128;
constexpr size_t ATTN_ELEMS = (size_t)BH * N * M;     // 134217728
constexpr size_t QKV_ELEMS  = (size_t)BH * N * D;     // 8388608
constexpr int PB_BLOCKS = 2048;
constexpr int KCONV_BLOCKS = 512;
constexpr int COPY_BLOCKS_PER = 256;                   // per q/v tensor
constexpr int BGROUP = 4;                              // batches per attn block
constexpr int BR = 32, BC = 256;                       // attn tile: 32 rows x 256 cols

__device__ __forceinline__ short f2b(float x) {
    __hip_bfloat16 h = __float2bfloat16(x);
    return *reinterpret_cast<short*>(&h);
}

__device__ __forceinline__ void gl_lds16(const void* g, void* l) {
    __builtin_amdgcn_global_load_lds(
        (const __attribute__((address_space(1))) u32*)g,
        (__attribute__((address_space(3))) u32*)l, 16, 0, 0);
}

// Fused prep (r6 structure + kconv dual-write):
//   [0, PB_BLOCKS)            : pb[n,m] = pos_enc[n,m,:].w + b
//   [.., +KCONV_BLOCKS)       : keys -> kbf (bf16, pre-swizzled) AND kout
//                               (fp32 pass-through; second read L2-hits)
//   [.., +ncopy)              : q/v pass-through copies
//   last                      : scale = sum(w)/sqrt(16)
__global__ void prep_kernel(const float* __restrict__ q, const float* __restrict__ k,
                            const float* __restrict__ v, const float* __restrict__ pos,
                            const float* __restrict__ w, const float* __restrict__ b,
                            float* __restrict__ pb, short* __restrict__ kbf,
                            float* __restrict__ scale_p,
                            float* __restrict__ qout, float* __restrict__ kout,
                            float* __restrict__ vout, int ncopy) {
    const int bid = blockIdx.x, tid = threadIdx.x;
    if (bid < PB_BLOCKS) {
        const int lane16 = tid & 15;
        const f32x4 w4 = ((const f32x4*)w)[lane16];
        const float bias = b[0];
        const int group = (bid * 256 + tid) >> 4;
        const int ngroups = (PB_BLOCKS * 256) >> 4;
        for (int pair = group; pair < N * M; pair += ngroups) {
            f32x4 p = __builtin_nontemporal_load((const f32x4*)pos + (size_t)pair * 16 + lane16);
            float s = p[0]*w4[0] + p[1]*w4[1] + p[2]*w4[2] + p[3]*w4[3];
            s += __shfl_xor(s, 1);
            s += __shfl_xor(s, 2);
            s += __shfl_xor(s, 4);
            s += __shfl_xor(s, 8);
            if (lane16 == 0) pb[pair] = s + bias;
        }
    } else if (bid < PB_BLOCKS + KCONV_BLOCKS) {
        const int cid = bid - PB_BLOCKS;
        const int total_slots = BH * N * 8;        // 16B slots, 1048576
        for (int gs = cid * 256 + tid; gs < total_slots; gs += KCONV_BLOCKS * 256) {
            const int qs = gs & 7, gr = (gs >> 3) & (N - 1), bb = gs >> 13;
            const float* rowp = k + ((size_t)bb * N + gr) * D;
            // swizzled read -> kbf (bf16)
            const float* src = rowp + (qs ^ (gr & 7)) * 8;
            f32x4 x0 = ((const f32x4*)src)[0], x1 = ((const f32x4*)src)[1];
            short8 pk;
#pragma unroll
            for (int e = 0; e < 4; e++) { pk[e] = f2b(x0[e]); pk[4 + e] = f2b(x1[e]); }
            *(short8*)&kbf[(size_t)gs * 8] = pk;
            // linear read (same L2 lines) -> kout fp32 pass-through
            f32x4 y0 = ((const f32x4*)(rowp + qs * 8))[0];
            f32x4 y1 = ((const f32x4*)(rowp + qs * 8))[1];
            __builtin_nontemporal_store(y0, (f32x4*)(kout + (size_t)gs * 8));
            __builtin_nontemporal_store(y1, (f32x4*)(kout + (size_t)gs * 8) + 1);
        }
    } else if (bid < PB_BLOCKS + KCONV_BLOCKS + ncopy) {
        const int cid = bid - PB_BLOCKS - KCONV_BLOCKS;
        const int which = cid >> 8, lid = cid & 255;
        const f32x4* __restrict__ src = (which == 0) ? (const f32x4*)q : (const f32x4*)v;
        f32x4* __restrict__ dst = (which == 0) ? (f32x4*)qout : (f32x4*)vout;
        const int nel4 = (int)(QKV_ELEMS / 4);
        for (int i = lid * 256 + tid; i < nel4; i += COPY_BLOCKS_PER * 256) {
            f32x4 x = __builtin_nontemporal_load(src + i);
            __builtin_nontemporal_store(x, dst + i);
        }
    } else {
        if (tid < 64) {
            float val = w[tid];
#pragma unroll
            for (int o = 32; o > 0; o >>= 1) val += __shfl_down(val, o);
            if (tid == 0) scale_p[0] = val * 0.25f;
        }
    }
}

// attn = (K K^T)*scale + pb.  r6 structure EXACTLY (32x256 tile, single 36KB
// buffer, plain __syncthreads, pf in registers, gl_lds staging from
// pre-swizzled bf16 keys, plain stores).  BGROUP=4 -> 4096 blocks for finer
// cohort scheduling; staged-bytes ratio unchanged (1.125).
__launch_bounds__(256)
__global__ void attn_kernel(const short* __restrict__ kbf, const float* __restrict__ pb,
                            const float* __restrict__ scale_p, float* __restrict__ out) {
    __shared__ short lK[(BR + BC) * 64];          // 36KB
    const int pos = blockIdx.x;                   // 0..127
    const int tr = pos >> 2, tc = pos & 3;        // 32 row-tiles x 4 col-tiles
    const int batch0 = blockIdx.y * BGROUP;
    const int tid = threadIdx.x;
    const float scale = scale_p[0];

    const int lane = tid & 63, wv = tid >> 6;     // 4 waves
    const int wr = wv >> 1, wc = wv & 1;          // 2x2: 16 rows x 128 cols each
    const int frow = lane & 15;
    const int kslot = lane >> 4;

    const int orow = tr * BR + wr * 16 + (lane >> 4) * 4;   // + r
    const int ocol = tc * BC + wc * 128 + (lane & 15);      // + j*16

    // pb fragments in accumulator layout — reused for all BGROUP batches.
    f32x4 pf[8];
#pragma unroll
    for (int j = 0; j < 8; j++)
#pragma unroll
        for (int r = 0; r < 4; r++)
            pf[j][r] = pb[(size_t)(orow + r) * M + (ocol + j * 16)];

    for (int t = 0; t < BGROUP; ++t) {
        const short* __restrict__ Kb = kbf + (size_t)(batch0 + t) * N * 64;

        // Stage A rows [tr*32,+32) and B rows [tc*256,+256): 2304 16B slots,
        // direct global->LDS (source pre-swizzled, LDS linear).
#pragma unroll
        for (int it = 0; it < 9; ++it) {
            const int slot = it * 256 + tid;
            const int row = slot >> 3, qs = slot & 7;
            const int gr = (row < BR) ? (tr * BR + row) : (tc * BC + (row - BR));
            gl_lds16(Kb + (size_t)gr * 64 + qs * 8, &lK[slot * 8]);
        }
        __syncthreads();

        f32x4 acc[8] = {};
#pragma unroll
        for (int h = 0; h < 2; ++h) {             // k halves (k=0..31, 32..63)
            const int ra = wr * 16 + frow;
            short8 a = *(const short8*)&lK[ra * 64 + ((h * 4 + kslot) ^ (ra & 7)) * 8];
#pragma unroll
            for (int j = 0; j < 8; ++j) {
                const int rb = BR + wc * 128 + j * 16 + frow;
                short8 bf = *(const short8*)&lK[rb * 64 + ((h * 4 + kslot) ^ (rb & 7)) * 8];
                acc[j] = __builtin_amdgcn_mfma_f32_16x16x32_bf16(a, bf, acc[j], 0, 0, 0);
            }
        }

        const size_t obase = (size_t)(batch0 + t) * N * M;
#pragma unroll
        for (int j = 0; j < 8; ++j)
#pragma unroll
            for (int r = 0; r < 4; ++r) {
                out[obase + (size_t)(orow + r) * M + (ocol + j * 16)]
                    = acc[j][r] * scale + pf[j][r];
            }
        __syncthreads();                          // LDS safe to overwrite next t
    }
}

extern "C" void kernel_launch(void* const* d_in, const int* in_sizes, int n_in,
                              void* d_out, int out_size, void* d_ws, size_t ws_size,
                              hipStream_t stream) {
    const float* queries = (const float*)d_in[0];
    const float* keys    = (const float*)d_in[1];
    const float* values  = (const float*)d_in[2];
    const float* pos_enc = (const float*)d_in[3];
    const float* w_pos   = (const float*)d_in[4];
    const float* b_pos   = (const float*)d_in[5];

    float* out  = (float*)d_out;
    float* qout = out + ATTN_ELEMS;
    float* kout = qout + QKV_ELEMS;
    float* vout = kout + QKV_ELEMS;

    // ws layout: pb (N*M floats) | scale (16 floats) | kbf (BH*N*64 shorts)
    const size_t need_ws = ((size_t)N * M + 16) * sizeof(float)
                         + (size_t)BH * N * 64 * sizeof(short);
    const int npos = (N / BR) * (M / BC);         // 128 tile positions

    if (ws_size >= need_ws) {
        float* pb      = (float*)d_ws;
        float* scale_p = pb + (size_t)N * M;
        short* kbf     = (short*)(scale_p + 16);
        const int ncopy = 2 * COPY_BLOCKS_PER;    // q and v only; k via kconv
        prep_kernel<<<dim3(PB_BLOCKS + KCONV_BLOCKS + ncopy + 1), dim3(256), 0, stream>>>(
            queries, keys, values, pos_enc, w_pos, b_pos, pb, kbf, scale_p,
            qout, kout, vout, ncopy);
        attn_kernel<<<dim3(npos, BH / BGROUP), dim3(256), 0, stream>>>(kbf, pb, scale_p, out);
    } else {
        // Fallback: stash pb + scale + kbf in the q-region of d_out (20MB);
        // kconv still dual-writes kout (separate region); copy q/v after attn.
        float* pb      = qout;
        float* scale_p = pb + (size_t)N * M;
        short* kbf     = (short*)(scale_p + 16);
        prep_kernel<<<dim3(PB_BLOCKS + KCONV_BLOCKS + 1), dim3(256), 0, stream>>>(
            queries, keys, values, pos_enc, w_pos, b_pos, pb, kbf, scale_p,
            qout, kout, vout, /*ncopy=*/0);
        attn_kernel<<<dim3(npos, BH / BGROUP), dim3(256), 0, stream>>>(kbf, pb, scale_p, out);
        hipMemcpyAsync(qout, queries, QKV_ELEMS * sizeof(float), hipMemcpyDeviceToDevice, stream);
        hipMemcpyAsync(vout, values,  QKV_ELEMS * sizeof(float), hipMemcpyDeviceToDevice, stream);
    }
}